// Round 3
// baseline (153.675 us; speedup 1.0000x reference)
//
#include <hip/hip_runtime.h>
#include <math.h>

// Problem constants
constexpr int B = 4, S = 4096, N = 16, D = 64, M = 4;
constexpr int SND = S * N * D;      // 4,194,304 (b stride for q/k/v)
constexpr int ND  = N * D;          // 1024 (s stride)
constexpr int DD  = D * D;          // 4096

// ---------------------------------------------------------------------------
// Kernel 1: partial outer-product accumulation, register-only streaming.
//   part[bn][chunk][k][v] = sum_{s in chunk} k[b,s,n,k] * v[b,s,n,v]
// grid = (64, nchunks), block = 256 = 4 waves.
// Each wave owns one 32x32 quadrant of the 64x64 output -> no LDS, no
// barriers, 4x4 register tile per lane, 2 float4 loads per s-row.
// Same-address lanes coalesce; cross-wave 2x redundancy is L1-absorbed.
// ---------------------------------------------------------------------------
__global__ __launch_bounds__(256) void k1_partials(const float* __restrict__ kg,
                                                   const float* __restrict__ vg,
                                                   float* __restrict__ part,
                                                   int spb) {
  const int t = threadIdx.x;
  const int bn = blockIdx.x;
  const int b = bn >> 4, n = bn & 15;
  const int w = t >> 6;            // wave 0..3 -> quadrant
  const int l = t & 63;
  const int k0 = (w >> 1) * 32 + (l >> 3) * 4;   // 8x8 lane grid in quadrant
  const int v0 = (w & 1) * 32 + (l & 7) * 4;

  const size_t base = (size_t)b * SND + (size_t)n * D +
                      (size_t)(blockIdx.y * spb) * ND;
  const float* kp = kg + base + k0;
  const float* vp = vg + base + v0;

  float acc[4][4] = {};

  const int niter = spb >> 3;      // unroll s by 8
  for (int it = 0; it < niter; ++it) {
    float4 ka[8], va[8];
#pragma unroll
    for (int u = 0; u < 8; ++u) {
      ka[u] = *(const float4*)(kp + (size_t)u * ND);
      va[u] = *(const float4*)(vp + (size_t)u * ND);
    }
#pragma unroll
    for (int u = 0; u < 8; ++u) {
      const float kk[4] = {ka[u].x, ka[u].y, ka[u].z, ka[u].w};
      const float vv[4] = {va[u].x, va[u].y, va[u].z, va[u].w};
#pragma unroll
      for (int i = 0; i < 4; ++i)
#pragma unroll
        for (int j = 0; j < 4; ++j) acc[i][j] += kk[i] * vv[j];
    }
    kp += 8 * ND;
    vp += 8 * ND;
  }

  float* p = part + ((size_t)bn * gridDim.y + blockIdx.y) * DD;
#pragma unroll
  for (int i = 0; i < 4; ++i) {
    *(float4*)&p[(k0 + i) * D + v0] =
        make_float4(acc[i][0], acc[i][1], acc[i][2], acc[i][3]);
  }
}

// ---------------------------------------------------------------------------
// Kernel 2: combine partials + memory term into Meff[bn][k][v]
//   Meff = sum_m gates[m]*sig[m]*memory[b,m,n] + (sum_m gates[m]*(1-sig[m])) * new_info
// grid = (64, 16), block = 256 — one thread per kv element
// ---------------------------------------------------------------------------
__global__ __launch_bounds__(256) void k2_combine(const float* __restrict__ part,
                                                  const float* __restrict__ memg,
                                                  const float* __restrict__ decay,
                                                  const float* __restrict__ gatew,
                                                  float* __restrict__ meff,
                                                  int nchunks) {
  const int t = threadIdx.x;
  const int bn = blockIdx.x;
  const int b = bn >> 4, n = bn & 15;
  const int kv = blockIdx.y * 256 + t;

  float gw[M], df[M];
#pragma unroll
  for (int m = 0; m < M; ++m) { gw[m] = gatew[m]; df[m] = decay[m]; }
  const float mx = fmaxf(fmaxf(gw[0], gw[1]), fmaxf(gw[2], gw[3]));
  float e[M], esum = 0.f;
#pragma unroll
  for (int m = 0; m < M; ++m) { e[m] = expf(gw[m] - mx); esum += e[m]; }
  float w[M], c = 0.f;
#pragma unroll
  for (int m = 0; m < M; ++m) {
    const float g = e[m] / esum;
    const float sg = 1.f / (1.f + expf(-df[m]));
    w[m] = g * sg;
    c += g * (1.f - sg);
  }

  const float* pb = part + (size_t)bn * nchunks * DD + kv;
  float ni = 0.f;
  for (int ch = 0; ch < nchunks; ++ch) ni += pb[(size_t)ch * DD];
  float a = c * ni;
#pragma unroll
  for (int m = 0; m < M; ++m)
    a += w[m] * memg[(((size_t)b * M + m) * N + n) * DD + kv];
  meff[(size_t)bn * DD + kv] = a;
}

// ---------------------------------------------------------------------------
// Kernel 3: out[b,s,n,v] = sum_k q[b,s,n,k] * Meff[bn][k][v]
// grid = (64, 64), block = 256; 64 s-rows per block.
// Meff stays in LDS (high reuse); q is streamed from global (single-use,
// 16B granules dedup across the 16 lanes sharing a row).
// ---------------------------------------------------------------------------
__global__ __launch_bounds__(256) void k3_out(const float* __restrict__ qg,
                                              const float* __restrict__ meff,
                                              float* __restrict__ outg) {
  __shared__ __align__(16) float Ms[64 * 64];   // Meff[k][v]

  const int t = threadIdx.x;
  const int bn = blockIdx.x;
  const int b = bn >> 4, n = bn & 15;
  const int s0 = blockIdx.y * 64;

  const float4* mp4 = (const float4*)(meff + (size_t)bn * DD);
#pragma unroll
  for (int i = 0; i < 4; ++i) ((float4*)Ms)[t + i * 256] = mp4[t + i * 256];
  __syncthreads();

  const size_t qbase = (size_t)b * SND + (size_t)s0 * ND + (size_t)n * D;
  const int r0 = (t >> 4) * 4;   // 4 s-rows
  const int v0 = (t & 15) * 4;   // 4 v cols
  float acc[4][4] = {};

#pragma unroll 4
  for (int k4 = 0; k4 < 16; ++k4) {
    float4 qv[4], mv[4];
#pragma unroll
    for (int i = 0; i < 4; ++i)
      qv[i] = *(const float4*)(qg + qbase + (size_t)(r0 + i) * ND + k4 * 4);
#pragma unroll
    for (int i = 0; i < 4; ++i)
      mv[i] = *(const float4*)&Ms[(k4 * 4 + i) * D + v0];

#pragma unroll
    for (int r = 0; r < 4; ++r) {
      const float qa[4] = {qv[r].x, qv[r].y, qv[r].z, qv[r].w};
      const float ma0[4] = {mv[0].x, mv[0].y, mv[0].z, mv[0].w};
      const float ma1[4] = {mv[1].x, mv[1].y, mv[1].z, mv[1].w};
      const float ma2[4] = {mv[2].x, mv[2].y, mv[2].z, mv[2].w};
      const float ma3[4] = {mv[3].x, mv[3].y, mv[3].z, mv[3].w};
#pragma unroll
      for (int j = 0; j < 4; ++j)
        acc[r][j] += qa[0] * ma0[j] + qa[1] * ma1[j] + qa[2] * ma2[j] + qa[3] * ma3[j];
    }
  }

#pragma unroll
  for (int i = 0; i < 4; ++i) {
    *(float4*)&outg[qbase + (size_t)(r0 + i) * ND + v0] =
        make_float4(acc[i][0], acc[i][1], acc[i][2], acc[i][3]);
  }
}

// ---------------------------------------------------------------------------
extern "C" void kernel_launch(void* const* d_in, const int* in_sizes, int n_in,
                              void* d_out, int out_size, void* d_ws, size_t ws_size,
                              hipStream_t stream) {
  const float* q     = (const float*)d_in[0];
  const float* k     = (const float*)d_in[1];
  const float* v     = (const float*)d_in[2];
  const float* memg  = (const float*)d_in[3];
  const float* decay = (const float*)d_in[4];
  const float* gatew = (const float*)d_in[5];
  float* out = (float*)d_out;

  float* meff = (float*)d_ws;                 // 64*4096 floats = 1 MB
  float* part = meff + (size_t)64 * DD;       // nchunks MB after that

  // pick partial-chunk count that fits in ws
  const size_t meff_bytes = (size_t)64 * DD * sizeof(float);
  const size_t avail = ws_size > meff_bytes ? ws_size - meff_bytes : 0;
  int nchunks = 16;
  while (nchunks > 1 && (size_t)nchunks * 64 * DD * sizeof(float) > avail)
    nchunks >>= 1;
  const int spb = S / nchunks;

  hipLaunchKernelGGL(k1_partials, dim3(64, nchunks), dim3(256), 0, stream,
                     k, v, part, spb);
  hipLaunchKernelGGL(k2_combine, dim3(64, 16), dim3(256), 0, stream,
                     part, memg, decay, gatew, meff, nchunks);
  hipLaunchKernelGGL(k3_out, dim3(64, 64), dim3(256), 0, stream,
                     q, meff, out);
}

// Round 4
// 101.584 us; speedup vs baseline: 1.5128x; 1.5128x over previous
//
#include <hip/hip_runtime.h>
#include <math.h>

// Problem constants
constexpr int B = 4, S = 4096, N = 16, D = 64, M = 4;
constexpr int SND = S * N * D;      // 4,194,304 (b stride for q/k/v)
constexpr int ND  = N * D;          // 1024 (s stride)
constexpr int DD  = D * D;          // 4096

// ---------------------------------------------------------------------------
// Kernel 1: partial outer-product accumulation
//   part[bn][chunk][k][v] = sum_{s in chunk} k[b,s,n,k] * v[b,s,n,v]
// grid = (64, nchunks), block = 256. Double-buffered LDS, reg-prefetch.
// (round-2 structure: 53us @ nchunks=16; this round nchunks=32 for occupancy)
// ---------------------------------------------------------------------------
__global__ __launch_bounds__(256) void k1_partials(const float* __restrict__ kg,
                                                   const float* __restrict__ vg,
                                                   float* __restrict__ part,
                                                   int spb) {
  __shared__ __align__(16) float kb[2][16 * 64];
  __shared__ __align__(16) float vb[2][16 * 64];

  const int t = threadIdx.x;
  const int bn = blockIdx.x;
  const int b = bn >> 4, n = bn & 15;
  const size_t base = (size_t)b * SND + (size_t)n * D;
  const int s0 = blockIdx.y * spb;

  const int row = t >> 4;          // 0..15  (staging row)
  const int d4  = (t & 15) * 4;    // 0..60  (staging col, float4)
  const int k0  = (t >> 4) * 4;    // compute tile: k rows
  const int v0  = (t & 15) * 4;    // compute tile: v cols

  float acc[4][4] = {};

  const float* kp = kg + base + (size_t)(s0 + row) * ND + d4;
  const float* vp = vg + base + (size_t)(s0 + row) * ND + d4;
  float4 kl = *(const float4*)kp;
  float4 vl = *(const float4*)vp;

  const int niter = spb >> 4;
  for (int it = 0; it < niter; ++it) {
    const int cur = it & 1;
    *(float4*)&kb[cur][row * 64 + d4] = kl;
    *(float4*)&vb[cur][row * 64 + d4] = vl;
    if (it + 1 < niter) {               // prefetch next stage into regs
      kp += 16 * ND; vp += 16 * ND;
      kl = *(const float4*)kp;
      vl = *(const float4*)vp;
    }
    __syncthreads();                    // buf[cur] visible; prev-parity reads done
#pragma unroll
    for (int ss = 0; ss < 16; ++ss) {
      const float4 kk4 = *(const float4*)&kb[cur][ss * 64 + k0];
      const float4 vv4 = *(const float4*)&vb[cur][ss * 64 + v0];
      const float ka[4] = {kk4.x, kk4.y, kk4.z, kk4.w};
      const float va[4] = {vv4.x, vv4.y, vv4.z, vv4.w};
#pragma unroll
      for (int i = 0; i < 4; ++i)
#pragma unroll
        for (int j = 0; j < 4; ++j) acc[i][j] += ka[i] * va[j];
    }
  }

  float* p = part + ((size_t)bn * gridDim.y + blockIdx.y) * DD;
#pragma unroll
  for (int i = 0; i < 4; ++i) {
    *(float4*)&p[(k0 + i) * D + v0] =
        make_float4(acc[i][0], acc[i][1], acc[i][2], acc[i][3]);
  }
}

// ---------------------------------------------------------------------------
// Kernel 2: combine partials + memory term into Meff[bn][k][v]
//   Meff = sum_m gates[m]*sig[m]*memory[b,m,n] + (sum_m gates[m]*(1-sig[m])) * new_info
// grid = (64, 16), block = 256 — one thread per kv element
// ---------------------------------------------------------------------------
__global__ __launch_bounds__(256) void k2_combine(const float* __restrict__ part,
                                                  const float* __restrict__ memg,
                                                  const float* __restrict__ decay,
                                                  const float* __restrict__ gatew,
                                                  float* __restrict__ meff,
                                                  int nchunks) {
  const int t = threadIdx.x;
  const int bn = blockIdx.x;
  const int b = bn >> 4, n = bn & 15;
  const int kv = blockIdx.y * 256 + t;

  float gw[M], df[M];
#pragma unroll
  for (int m = 0; m < M; ++m) { gw[m] = gatew[m]; df[m] = decay[m]; }
  const float mx = fmaxf(fmaxf(gw[0], gw[1]), fmaxf(gw[2], gw[3]));
  float e[M], esum = 0.f;
#pragma unroll
  for (int m = 0; m < M; ++m) { e[m] = expf(gw[m] - mx); esum += e[m]; }
  float w[M], c = 0.f;
#pragma unroll
  for (int m = 0; m < M; ++m) {
    const float g = e[m] / esum;
    const float sg = 1.f / (1.f + expf(-df[m]));
    w[m] = g * sg;
    c += g * (1.f - sg);
  }

  const float* pb = part + (size_t)bn * nchunks * DD + kv;
  float ni = 0.f;
  for (int ch = 0; ch < nchunks; ++ch) ni += pb[(size_t)ch * DD];
  float a = c * ni;
#pragma unroll
  for (int m = 0; m < M; ++m)
    a += w[m] * memg[(((size_t)b * M + m) * N + n) * DD + kv];
  meff[(size_t)bn * DD + kv] = a;
}

// ---------------------------------------------------------------------------
// Kernel 3: out[b,s,n,v] = sum_k q[b,s,n,k] * Meff[bn][k][v]
// grid = (64, 64), block = 256; 64 s-rows per block.
// Both Meff and q staged in LDS with coalesced float4 loads.
// ---------------------------------------------------------------------------
__global__ __launch_bounds__(256) void k3_out(const float* __restrict__ qg,
                                              const float* __restrict__ meff,
                                              float* __restrict__ outg) {
  __shared__ __align__(16) float Ms[64 * 64];   // Meff[k][v]
  __shared__ __align__(16) float qs[64 * 68];   // q[r][d], padded rows

  const int t = threadIdx.x;
  const int bn = blockIdx.x;
  const int b = bn >> 4, n = bn & 15;
  const int s0 = blockIdx.y * 64;

  const float4* mp4 = (const float4*)(meff + (size_t)bn * DD);
#pragma unroll
  for (int i = 0; i < 4; ++i) ((float4*)Ms)[t + i * 256] = mp4[t + i * 256];

  const size_t qbase = (size_t)b * SND + (size_t)s0 * ND + (size_t)n * D;
#pragma unroll
  for (int i = 0; i < 4; ++i) {
    const int idx = t + i * 256;       // float4 index: 64 rows x 16 per row
    const int r = idx >> 4, c4 = (idx & 15) * 4;
    *(float4*)&qs[r * 68 + c4] = *(const float4*)(qg + qbase + (size_t)r * ND + c4);
  }
  __syncthreads();

  const int r0 = (t >> 4) * 4;   // 4 s-rows
  const int v0 = (t & 15) * 4;   // 4 v cols
  float acc[4][4] = {};

#pragma unroll 4
  for (int k4 = 0; k4 < 16; ++k4) {
    float4 qv[4], mv[4];
#pragma unroll
    for (int i = 0; i < 4; ++i) {
      qv[i] = *(const float4*)&qs[(r0 + i) * 68 + k4 * 4];
      mv[i] = *(const float4*)&Ms[(k4 * 4 + i) * D + v0];
    }
#pragma unroll
    for (int r = 0; r < 4; ++r) {
      const float qa[4] = {qv[r].x, qv[r].y, qv[r].z, qv[r].w};
#pragma unroll
      for (int j = 0; j < 4; ++j) {
        const float mj[4] = {mv[0].x, mv[1].x, mv[2].x, mv[3].x};
        (void)mj;
      }
      acc[r][0] += qa[0] * mv[0].x + qa[1] * mv[1].x + qa[2] * mv[2].x + qa[3] * mv[3].x;
      acc[r][1] += qa[0] * mv[0].y + qa[1] * mv[1].y + qa[2] * mv[2].y + qa[3] * mv[3].y;
      acc[r][2] += qa[0] * mv[0].z + qa[1] * mv[1].z + qa[2] * mv[2].z + qa[3] * mv[3].z;
      acc[r][3] += qa[0] * mv[0].w + qa[1] * mv[1].w + qa[2] * mv[2].w + qa[3] * mv[3].w;
    }
  }

#pragma unroll
  for (int i = 0; i < 4; ++i) {
    *(float4*)&outg[qbase + (size_t)(r0 + i) * ND + v0] =
        make_float4(acc[i][0], acc[i][1], acc[i][2], acc[i][3]);
  }
}

// ---------------------------------------------------------------------------
extern "C" void kernel_launch(void* const* d_in, const int* in_sizes, int n_in,
                              void* d_out, int out_size, void* d_ws, size_t ws_size,
                              hipStream_t stream) {
  const float* q     = (const float*)d_in[0];
  const float* k     = (const float*)d_in[1];
  const float* v     = (const float*)d_in[2];
  const float* memg  = (const float*)d_in[3];
  const float* decay = (const float*)d_in[4];
  const float* gatew = (const float*)d_in[5];
  float* out = (float*)d_out;

  float* meff = (float*)d_ws;                 // 64*4096 floats = 1 MB
  float* part = meff + (size_t)64 * DD;       // nchunks MB after that

  // pick partial-chunk count that fits in ws (prefer 32 for occupancy)
  const size_t meff_bytes = (size_t)64 * DD * sizeof(float);
  const size_t avail = ws_size > meff_bytes ? ws_size - meff_bytes : 0;
  int nchunks = 32;
  while (nchunks > 1 && (size_t)nchunks * 64 * DD * sizeof(float) > avail)
    nchunks >>= 1;
  const int spb = S / nchunks;

  hipLaunchKernelGGL(k1_partials, dim3(64, nchunks), dim3(256), 0, stream,
                     k, v, part, spb);
  hipLaunchKernelGGL(k2_combine, dim3(64, 16), dim3(256), 0, stream,
                     part, memg, decay, gatew, meff, nchunks);
  hipLaunchKernelGGL(k3_out, dim3(64, 64), dim3(256), 0, stream,
                     q, meff, out);
}

// Round 5
// 71.274 us; speedup vs baseline: 2.1561x; 1.4253x over previous
//
#include <hip/hip_runtime.h>
#include <hip/hip_bf16.h>
#include <math.h>

// Problem constants
constexpr int B = 4, S = 4096, N = 16, D = 64, M = 4;
constexpr int SND = S * N * D;      // b stride for q/k/v
constexpr int ND  = N * D;          // s stride
constexpr int DD  = D * D;          // 4096

typedef __attribute__((ext_vector_type(8))) short bf16x8;
typedef __attribute__((ext_vector_type(4))) float f32x4;
typedef unsigned short ushort_t;
typedef unsigned int uint_t;

__device__ inline ushort_t f2bf(float x) {
  __hip_bfloat16 h = __float2bfloat16(x);   // RNE
  return __builtin_bit_cast(ushort_t, h);
}

// ---------------------------------------------------------------------------
// Kernel 1: part[bn][chunk] = sum_{s in chunk} K[s,:]^T ⊗ V[s,:]  via MFMA.
// grid = (64 bn, nchunks), block = 256 (4 waves).
// LDS: transposed bf16 tiles kT[d][s], vT[d][s], 64x64 per stage, XOR-swizzled
// slots (T2) so per-fragment ds_read_b128 is conflict-free. Double-buffered,
// one barrier per stage; global loads issued a stage ahead (T14).
// Wave w owns a 32x32 output quadrant: 2x2 MFMA tiles of 16x16x32_bf16.
// ---------------------------------------------------------------------------
__global__ __launch_bounds__(256) void k1_partials(const float* __restrict__ kg,
                                                   const float* __restrict__ vg,
                                                   float* __restrict__ part,
                                                   int spb) {
  __shared__ ushort_t kT[2][64][64];
  __shared__ ushort_t vT[2][64][64];

  const int t = threadIdx.x, w = t >> 6, l = t & 63;
  const int bn = blockIdx.x;
  const int b = bn >> 4, n = bn & 15;
  const size_t base = (size_t)b * SND + (size_t)n * D +
                      (size_t)blockIdx.y * spb * ND;

  // staging coords: even stage-local s row + 8-wide d group
  const int ss2 = 16 * w + 2 * (l >> 3);   // 0..62 even
  const int d8  = (l & 7) * 8;
  // compute coords
  const int m0  = (w >> 1) * 32, n0w = (w & 1) * 32;
  const int lr  = l & 15, lg = l >> 4;

  f32x4 acc[2][2];
#pragma unroll
  for (int i = 0; i < 2; ++i)
#pragma unroll
    for (int j = 0; j < 2; ++j) acc[i][j] = (f32x4)0.f;

  float ka[8], kb2[8], va[8], vb2[8];      // staging regs (2 s-rows x 8 d)

#define K1_LOAD(st)                                                         \
  {                                                                         \
    const float* kp = kg + base + (size_t)((st) * 64 + ss2) * ND + d8;      \
    const float* vp = vg + base + (size_t)((st) * 64 + ss2) * ND + d8;      \
    *(float4*)&ka[0]  = *(const float4*)kp;                                 \
    *(float4*)&ka[4]  = *(const float4*)(kp + 4);                           \
    *(float4*)&kb2[0] = *(const float4*)(kp + ND);                          \
    *(float4*)&kb2[4] = *(const float4*)(kp + ND + 4);                      \
    *(float4*)&va[0]  = *(const float4*)vp;                                 \
    *(float4*)&va[4]  = *(const float4*)(vp + 4);                           \
    *(float4*)&vb2[0] = *(const float4*)(vp + ND);                          \
    *(float4*)&vb2[4] = *(const float4*)(vp + ND + 4);                      \
  }

#define K1_WRITE(buf)                                                       \
  {                                                                         \
    const int sl = ss2 >> 3, sw = ss2 & 7;                                  \
    _Pragma("unroll")                                                       \
    for (int i = 0; i < 8; ++i) {                                           \
      const int off = (((sl) ^ i) << 3) + sw;   /* row&7 == i */            \
      *(uint_t*)&kT[buf][d8 + i][off] =                                     \
          (uint_t)f2bf(ka[i]) | ((uint_t)f2bf(kb2[i]) << 16);               \
      *(uint_t*)&vT[buf][d8 + i][off] =                                     \
          (uint_t)f2bf(va[i]) | ((uint_t)f2bf(vb2[i]) << 16);               \
    }                                                                       \
  }

  K1_LOAD(0);
  K1_WRITE(0);

  const int nst = spb >> 6;
  for (int st = 0; st < nst; ++st) {
    if (st + 1 < nst) K1_LOAD(st + 1);
    __syncthreads();                       // stage st writes visible
    const int buf = st & 1;
#pragma unroll
    for (int ks = 0; ks < 2; ++ks) {
      const int sp = ((4 * ks + lg) ^ (lr & 7)) << 3;  // swizzled elem off
      bf16x8 a0 = *(const bf16x8*)&kT[buf][m0 + lr][sp];
      bf16x8 a1 = *(const bf16x8*)&kT[buf][m0 + 16 + lr][sp];
      bf16x8 b0 = *(const bf16x8*)&vT[buf][n0w + lr][sp];
      bf16x8 b1 = *(const bf16x8*)&vT[buf][n0w + 16 + lr][sp];
      acc[0][0] = __builtin_amdgcn_mfma_f32_16x16x32_bf16(a0, b0, acc[0][0], 0, 0, 0);
      acc[0][1] = __builtin_amdgcn_mfma_f32_16x16x32_bf16(a0, b1, acc[0][1], 0, 0, 0);
      acc[1][0] = __builtin_amdgcn_mfma_f32_16x16x32_bf16(a1, b0, acc[1][0], 0, 0, 0);
      acc[1][1] = __builtin_amdgcn_mfma_f32_16x16x32_bf16(a1, b1, acc[1][1], 0, 0, 0);
    }
    if (st + 1 < nst) K1_WRITE((st + 1) & 1);  // other buffer: race-free
  }

  float* p = part + ((size_t)bn * gridDim.y + blockIdx.y) * DD;
#pragma unroll
  for (int mi = 0; mi < 2; ++mi)
#pragma unroll
    for (int ni = 0; ni < 2; ++ni)
#pragma unroll
      for (int ri = 0; ri < 4; ++ri)
        p[(m0 + 16 * mi + 4 * lg + ri) * 64 + (n0w + 16 * ni + lr)] =
            acc[mi][ni][ri];
#undef K1_LOAD
#undef K1_WRITE
}

// ---------------------------------------------------------------------------
// Kernel 2: Meff = sum_m g[m]*sig[m]*memory[b,m,n] + (sum_m g[m](1-sig[m]))*new_info
// Emits bf16 TRANSPOSED meffT[bn][v][k] (B-fragment-friendly for k3).
// grid = (64 bn, 16), block = 256 — one thread per kv element.
// ---------------------------------------------------------------------------
__global__ __launch_bounds__(256) void k2_combine(const float* __restrict__ part,
                                                  const float* __restrict__ memg,
                                                  const float* __restrict__ decay,
                                                  const float* __restrict__ gatew,
                                                  ushort_t* __restrict__ meffT,
                                                  int nchunks) {
  const int t = threadIdx.x;
  const int bn = blockIdx.x;
  const int b = bn >> 4, n = bn & 15;
  const int kv = blockIdx.y * 256 + t;
  const int k = kv >> 6, v = kv & 63;

  float gw[M], df[M];
#pragma unroll
  for (int m = 0; m < M; ++m) { gw[m] = gatew[m]; df[m] = decay[m]; }
  const float mx = fmaxf(fmaxf(gw[0], gw[1]), fmaxf(gw[2], gw[3]));
  float e[M], esum = 0.f;
#pragma unroll
  for (int m = 0; m < M; ++m) { e[m] = expf(gw[m] - mx); esum += e[m]; }
  float wgt[M], c = 0.f;
#pragma unroll
  for (int m = 0; m < M; ++m) {
    const float g = e[m] / esum;
    const float sg = 1.f / (1.f + expf(-df[m]));
    wgt[m] = g * sg;
    c += g * (1.f - sg);
  }

  const float* pb = part + (size_t)bn * nchunks * DD + kv;
  float ni = 0.f;
  for (int ch = 0; ch < nchunks; ++ch) ni += pb[(size_t)ch * DD];
  float a = c * ni;
#pragma unroll
  for (int m = 0; m < M; ++m)
    a += wgt[m] * memg[(((size_t)b * M + m) * N + n) * DD + kv];

  meffT[(size_t)bn * DD + v * 64 + k] = f2bf(a);
}

// ---------------------------------------------------------------------------
// Kernel 3: out[s,v] = q[s,:] @ Meff  via MFMA, LDS-free.
// grid = (64 bn, 16), block = 256 (4 waves); wave handles 64 s-rows x 64 v.
// A-frags (q): per-lane 8 contiguous k -> 2 global dwordx4 + cvt (no LDS).
// B-frags: bf16 meffT[v][k] rows, 1 dwordx4 per frag (L2-resident).
// ---------------------------------------------------------------------------
__global__ __launch_bounds__(256, 4) void k3_out(const float* __restrict__ qg,
                                                 const ushort_t* __restrict__ meffT,
                                                 float* __restrict__ outg) {
  const int t = threadIdx.x, w = t >> 6, l = t & 63;
  const int lr = l & 15, lg = l >> 4;
  const int bn = blockIdx.x;
  const int b = bn >> 4, n = bn & 15;
  const int s0 = blockIdx.y * 256 + w * 64;

  const ushort_t* mb = meffT + (size_t)bn * DD;
  bf16x8 bfr[4][2];
#pragma unroll
  for (int ni = 0; ni < 4; ++ni)
#pragma unroll
    for (int ks = 0; ks < 2; ++ks)
      bfr[ni][ks] = *(const bf16x8*)(mb + (16 * ni + lr) * 64 + 32 * ks + 8 * lg);

  f32x4 acc[4][4];
#pragma unroll
  for (int i = 0; i < 4; ++i)
#pragma unroll
    for (int j = 0; j < 4; ++j) acc[i][j] = (f32x4)0.f;

  const size_t qbase = (size_t)b * SND + (size_t)n * D;

#pragma unroll
  for (int mi = 0; mi < 4; ++mi) {
    const float* qr = qg + qbase + (size_t)(s0 + 16 * mi + lr) * ND + 8 * lg;
#pragma unroll
    for (int ks = 0; ks < 2; ++ks) {
      float qa[8];
      *(float4*)&qa[0] = *(const float4*)(qr + 32 * ks);
      *(float4*)&qa[4] = *(const float4*)(qr + 32 * ks + 4);
      bf16x8 a;
#pragma unroll
      for (int j = 0; j < 8; ++j) a[j] = (short)f2bf(qa[j]);
#pragma unroll
      for (int ni = 0; ni < 4; ++ni)
        acc[mi][ni] = __builtin_amdgcn_mfma_f32_16x16x32_bf16(a, bfr[ni][ks],
                                                              acc[mi][ni], 0, 0, 0);
    }
  }

#pragma unroll
  for (int mi = 0; mi < 4; ++mi)
#pragma unroll
    for (int ni = 0; ni < 4; ++ni)
#pragma unroll
      for (int ri = 0; ri < 4; ++ri)
        outg[qbase + (size_t)(s0 + 16 * mi + 4 * lg + ri) * ND + 16 * ni + lr] =
            acc[mi][ni][ri];
}

// ---------------------------------------------------------------------------
extern "C" void kernel_launch(void* const* d_in, const int* in_sizes, int n_in,
                              void* d_out, int out_size, void* d_ws, size_t ws_size,
                              hipStream_t stream) {
  const float* q     = (const float*)d_in[0];
  const float* k     = (const float*)d_in[1];
  const float* v     = (const float*)d_in[2];
  const float* memg  = (const float*)d_in[3];
  const float* decay = (const float*)d_in[4];
  const float* gatew = (const float*)d_in[5];
  float* out = (float*)d_out;

  ushort_t* meffT = (ushort_t*)d_ws;                  // 64*4096*2B = 512 KB
  const size_t meffT_bytes = (size_t)64 * DD * sizeof(ushort_t);
  float* part = (float*)((char*)d_ws + meffT_bytes);

  const size_t avail = ws_size > meffT_bytes ? ws_size - meffT_bytes : 0;
  int nchunks = 16;
  while (nchunks > 1 && (size_t)nchunks * 64 * DD * sizeof(float) > avail)
    nchunks >>= 1;
  const int spb = S / nchunks;                        // multiple of 64

  hipLaunchKernelGGL(k1_partials, dim3(64, nchunks), dim3(256), 0, stream,
                     k, v, part, spb);
  hipLaunchKernelGGL(k2_combine, dim3(64, 16), dim3(256), 0, stream,
                     part, memg, decay, gatew, meffT, nchunks);
  hipLaunchKernelGGL(k3_out, dim3(64, 16), dim3(256), 0, stream,
                     q, meffT, out);
}

// Round 6
// 64.832 us; speedup vs baseline: 2.3704x; 1.0994x over previous
//
#include <hip/hip_runtime.h>
#include <hip/hip_bf16.h>
#include <math.h>

// Problem constants
constexpr int B = 4, S = 4096, N = 16, D = 64, M = 4;
constexpr int SND = S * N * D;      // b stride for q/k/v
constexpr int ND  = N * D;          // s stride
constexpr int DD  = D * D;          // 4096
constexpr int NCH = 8;              // k1 chunks
constexpr int SPB = S / NCH;        // 512 s per block (128 per wave, 4 tiles of 32)

typedef __attribute__((ext_vector_type(8))) short bf16x8;
typedef __attribute__((ext_vector_type(4))) float f32x4;
typedef unsigned short u16;
typedef unsigned int u32;

__device__ inline u16 f2bf(float x) {
  __hip_bfloat16 h = __float2bfloat16(x);   // RNE
  return __builtin_bit_cast(u16, h);
}

// ---------------------------------------------------------------------------
// Kernel 1: part[bn][chunk] = sum_{s in chunk} K[s,:]^T ⊗ V[s,:]  via MFMA.
// WAVE-AUTONOMOUS: each wave owns a private LDS region and stages its own
// 32-s double-buffered bf16 tiles kT[d][s], vT[d][s]. No __syncthreads in the
// s-loop (same-wave in-order LDS), waves free-run like k3. Each wave computes
// the full 64x64 outer product; one barrier pair for the final reduction.
// grid = (64 bn, NCH), block = 256 (4 waves).
// ---------------------------------------------------------------------------
__global__ __launch_bounds__(256) void k1_partials(const float* __restrict__ kg,
                                                   const float* __restrict__ vg,
                                                   float* __restrict__ part) {
  // [wave][buf][arr(k,v)][64 d][32 slots] bf16 = 64 KB total
  __shared__ u16 lds[4][2][2][64][32];

  const int t = threadIdx.x, w = t >> 6, l = t & 63;
  const int bn = blockIdx.x;
  const int b = bn >> 4, n = bn & 15;
  const int r = l & 7, c = l >> 3;      // staging: s-pair r, d-octet c
  const int lr = l & 15, lg = l >> 4;   // mfma lane coords

  const size_t base = (size_t)b * SND + (size_t)n * D +
                      ((size_t)blockIdx.y * SPB + (size_t)w * 128) * ND;

  f32x4 acc[4][4];
#pragma unroll
  for (int i = 0; i < 4; ++i)
#pragma unroll
    for (int j = 0; j < 4; ++j) acc[i][j] = (f32x4)0.f;

  float kfa[2][2][8], vfa[2][2][8];     // [h][sp][d-in-octet]

  // Load 32-s tile tt into regs: lane covers s = tt*32 + {16h + 2r + sp}, d = 8c..8c+7
#define STAGE_LOAD(tt)                                                        \
  {                                                                           \
    _Pragma("unroll") for (int h = 0; h < 2; ++h)                             \
    _Pragma("unroll") for (int sp = 0; sp < 2; ++sp) {                        \
      const float* kp =                                                       \
          kg + base + (size_t)((tt) * 32 + 16 * h + 2 * r + sp) * ND + 8 * c; \
      const float* vp =                                                       \
          vg + base + (size_t)((tt) * 32 + 16 * h + 2 * r + sp) * ND + 8 * c; \
      *(float4*)&kfa[h][sp][0] = *(const float4*)kp;                          \
      *(float4*)&kfa[h][sp][4] = *(const float4*)(kp + 4);                    \
      *(float4*)&vfa[h][sp][0] = *(const float4*)vp;                          \
      *(float4*)&vfa[h][sp][4] = *(const float4*)(vp + 4);                    \
    }                                                                         \
  }

  // Transposed bf16 store: element (d, s) at slot ((s>>3) ^ (d&3))*8 + (s&7)
#define STAGE_WRITE(buf)                                                      \
  {                                                                           \
    _Pragma("unroll") for (int h = 0; h < 2; ++h)                             \
    _Pragma("unroll") for (int dd = 0; dd < 8; ++dd) {                        \
      const int d = 8 * c + dd;                                               \
      const int slot = (((2 * h + (r >> 2)) ^ (d & 3)) << 3) + ((2 * r) & 7); \
      *(u32*)&lds[w][buf][0][d][slot] =                                       \
          (u32)f2bf(kfa[h][0][dd]) | ((u32)f2bf(kfa[h][1][dd]) << 16);        \
      *(u32*)&lds[w][buf][1][d][slot] =                                       \
          (u32)f2bf(vfa[h][0][dd]) | ((u32)f2bf(vfa[h][1][dd]) << 16);        \
    }                                                                         \
  }

  // One K=32 MFMA sweep over the 4x4 tile grid from buffer `buf`
#define COMPUTE(buf)                                                          \
  {                                                                           \
    bf16x8 af[4], bfq[4];                                                     \
    _Pragma("unroll") for (int mi = 0; mi < 4; ++mi) {                        \
      const int row = 16 * mi + lr;                                           \
      af[mi]  = *(const bf16x8*)&lds[w][buf][0][row][(lg ^ (row & 3)) << 3];  \
      bfq[mi] = *(const bf16x8*)&lds[w][buf][1][row][(lg ^ (row & 3)) << 3];  \
    }                                                                         \
    _Pragma("unroll") for (int mi = 0; mi < 4; ++mi)                          \
    _Pragma("unroll") for (int ni = 0; ni < 4; ++ni)                          \
      acc[mi][ni] = __builtin_amdgcn_mfma_f32_16x16x32_bf16(                  \
          af[mi], bfq[ni], acc[mi][ni], 0, 0, 0);                             \
  }

  STAGE_LOAD(0);
  STAGE_WRITE(0);
  STAGE_LOAD(1);
  COMPUTE(0);
  STAGE_WRITE(1);
  STAGE_LOAD(2);
  COMPUTE(1);
  STAGE_WRITE(0);
  STAGE_LOAD(3);
  COMPUTE(0);
  STAGE_WRITE(1);
  COMPUTE(1);

#undef STAGE_LOAD
#undef STAGE_WRITE
#undef COMPUTE

  // Cross-wave reduction: waves dump acc into LDS, then block-wide sum.
  __syncthreads();
  float* red = (float*)lds;             // 16384 floats = 64 KB
#pragma unroll
  for (int mi = 0; mi < 4; ++mi)
#pragma unroll
    for (int ni = 0; ni < 4; ++ni)
#pragma unroll
      for (int ri = 0; ri < 4; ++ri)
        red[w * 4096 + (16 * mi + 4 * lg + ri) * 64 + 16 * ni + lr] =
            acc[mi][ni][ri];
  __syncthreads();

  float* p = part + ((size_t)bn * NCH + blockIdx.y) * DD;
#pragma unroll
  for (int j = 0; j < 4; ++j) {
    const int e = t * 16 + 4 * j;
    const float4 a0 = *(const float4*)&red[e];
    const float4 a1 = *(const float4*)&red[4096 + e];
    const float4 a2 = *(const float4*)&red[8192 + e];
    const float4 a3 = *(const float4*)&red[12288 + e];
    *(float4*)&p[e] = make_float4(a0.x + a1.x + a2.x + a3.x,
                                  a0.y + a1.y + a2.y + a3.y,
                                  a0.z + a1.z + a2.z + a3.z,
                                  a0.w + a1.w + a2.w + a3.w);
  }
}

// ---------------------------------------------------------------------------
// Kernel 2: Meff = sum_m g[m]*sig[m]*memory[b,m,n] + (sum_m g[m](1-sig[m]))*new_info
// Emits bf16 TRANSPOSED meffT[bn][v][k]. grid = (64, 16), block = 256.
// ---------------------------------------------------------------------------
__global__ __launch_bounds__(256) void k2_combine(const float* __restrict__ part,
                                                  const float* __restrict__ memg,
                                                  const float* __restrict__ decay,
                                                  const float* __restrict__ gatew,
                                                  u16* __restrict__ meffT) {
  const int t = threadIdx.x;
  const int bn = blockIdx.x;
  const int b = bn >> 4, n = bn & 15;
  const int kv = blockIdx.y * 256 + t;
  const int k = kv >> 6, v = kv & 63;

  float gw[M], df[M];
#pragma unroll
  for (int m = 0; m < M; ++m) { gw[m] = gatew[m]; df[m] = decay[m]; }
  const float mx = fmaxf(fmaxf(gw[0], gw[1]), fmaxf(gw[2], gw[3]));
  float e[M], esum = 0.f;
#pragma unroll
  for (int m = 0; m < M; ++m) { e[m] = expf(gw[m] - mx); esum += e[m]; }
  float wgt[M], cc = 0.f;
#pragma unroll
  for (int m = 0; m < M; ++m) {
    const float g = e[m] / esum;
    const float sg = 1.f / (1.f + expf(-df[m]));
    wgt[m] = g * sg;
    cc += g * (1.f - sg);
  }

  const float* pb = part + (size_t)bn * NCH * DD + kv;
  float ni = 0.f;
#pragma unroll
  for (int ch = 0; ch < NCH; ++ch) ni += pb[(size_t)ch * DD];
  float a = cc * ni;
#pragma unroll
  for (int m = 0; m < M; ++m)
    a += wgt[m] * memg[(((size_t)b * M + m) * N + n) * DD + kv];

  meffT[(size_t)bn * DD + v * 64 + k] = f2bf(a);
}

// ---------------------------------------------------------------------------
// Kernel 3: out[s,v] = q[s,:] @ Meff  via MFMA, LDS-free, free-running.
// grid = (64 bn, 16), block = 256 (4 waves); wave handles 64 s-rows x 64 v.
// ---------------------------------------------------------------------------
__global__ __launch_bounds__(256, 4) void k3_out(const float* __restrict__ qg,
                                                 const u16* __restrict__ meffT,
                                                 float* __restrict__ outg) {
  const int t = threadIdx.x, w = t >> 6, l = t & 63;
  const int lr = l & 15, lg = l >> 4;
  const int bn = blockIdx.x;
  const int b = bn >> 4, n = bn & 15;
  const int s0 = blockIdx.y * 256 + w * 64;

  const u16* mb = meffT + (size_t)bn * DD;
  bf16x8 bfr[4][2];
#pragma unroll
  for (int ni = 0; ni < 4; ++ni)
#pragma unroll
    for (int ks = 0; ks < 2; ++ks)
      bfr[ni][ks] = *(const bf16x8*)(mb + (16 * ni + lr) * 64 + 32 * ks + 8 * lg);

  f32x4 acc[4][4];
#pragma unroll
  for (int i = 0; i < 4; ++i)
#pragma unroll
    for (int j = 0; j < 4; ++j) acc[i][j] = (f32x4)0.f;

  const size_t qbase = (size_t)b * SND + (size_t)n * D;

#pragma unroll
  for (int mi = 0; mi < 4; ++mi) {
    const float* qr = qg + qbase + (size_t)(s0 + 16 * mi + lr) * ND + 8 * lg;
#pragma unroll
    for (int ks = 0; ks < 2; ++ks) {
      float qa[8];
      *(float4*)&qa[0] = *(const float4*)(qr + 32 * ks);
      *(float4*)&qa[4] = *(const float4*)(qr + 32 * ks + 4);
      bf16x8 a;
#pragma unroll
      for (int j = 0; j < 8; ++j) a[j] = (short)f2bf(qa[j]);
#pragma unroll
      for (int ni = 0; ni < 4; ++ni)
        acc[mi][ni] = __builtin_amdgcn_mfma_f32_16x16x32_bf16(a, bfr[ni][ks],
                                                              acc[mi][ni], 0, 0, 0);
    }
  }

#pragma unroll
  for (int mi = 0; mi < 4; ++mi)
#pragma unroll
    for (int ni = 0; ni < 4; ++ni)
#pragma unroll
      for (int ri = 0; ri < 4; ++ri)
        outg[qbase + (size_t)(s0 + 16 * mi + 4 * lg + ri) * ND + 16 * ni + lr] =
            acc[mi][ni][ri];
}

// ---------------------------------------------------------------------------
extern "C" void kernel_launch(void* const* d_in, const int* in_sizes, int n_in,
                              void* d_out, int out_size, void* d_ws, size_t ws_size,
                              hipStream_t stream) {
  const float* q     = (const float*)d_in[0];
  const float* k     = (const float*)d_in[1];
  const float* v     = (const float*)d_in[2];
  const float* memg  = (const float*)d_in[3];
  const float* decay = (const float*)d_in[4];
  const float* gatew = (const float*)d_in[5];
  float* out = (float*)d_out;

  u16* meffT = (u16*)d_ws;                            // 512 KB
  const size_t meffT_bytes = (size_t)64 * DD * sizeof(u16);
  float* part = (float*)((char*)d_ws + meffT_bytes);  // NCH MB

  hipLaunchKernelGGL(k1_partials, dim3(64, NCH), dim3(256), 0, stream,
                     k, v, part);
  hipLaunchKernelGGL(k2_combine, dim3(64, 16), dim3(256), 0, stream,
                     part, memg, decay, gatew, meffT);
  hipLaunchKernelGGL(k3_out, dim3(64, 16), dim3(256), 0, stream,
                     q, meffT, out);
}